// Round 1
// baseline (101.595 us; speedup 1.0000x reference)
//
#include <hip/hip_runtime.h>
#include <math.h>

// Problem: out[b, p(i,j)] = sigmoid( relu( (x_i|x_j)@W1+b1 @ W2 + b2 ) @ W3 + b3 )
// Key identity: the net is LINEAR until the ReLU, so fold
//   A  = W1[0:4]@W2   (4x100)
//   Bm = W1[4:8]@W2   (4x100)
//   c  = b1@W2 + b2   (100)
// and per-node U[b,i] = x[b,i]*A + c, V[b,j] = x[b,j]*Bm. Then
//   out = sigmoid( sum_h W3[h]*relu(U[i,h]+V[j,h]) + b3 )
// 11.3 GFLOP -> ~160 MFLOP, no big intermediates.

namespace {
constexpr int B_    = 64;
constexpr int N_    = 128;
constexpr int F_    = 4;
constexpr int H_    = 100;
constexpr int TILE  = 32;
constexpr int NT    = N_ / TILE;            // 4 tiles per axis
constexpr int NTP   = NT * (NT + 1) / 2;    // 10 upper-tri tile pairs
constexpr int PAIRS = N_ * (N_ - 1) / 2;    // 8128
constexpr int LDH   = H_ + 1;               // 101: odd stride -> conflict-free phase 3
}

__global__ __launch_bounds__(256)
void pairnet_fused(const float* __restrict__ x,
                   const float* __restrict__ W1,
                   const float* __restrict__ b1,
                   const float* __restrict__ W2,
                   const float* __restrict__ b2,
                   const float* __restrict__ W3,
                   const float* __restrict__ b3,
                   float* __restrict__ out)
{
    __shared__ float A_s [F_][H_];
    __shared__ float Bm_s[F_][H_];
    __shared__ float c_s [H_];
    __shared__ float w3_s[H_];
    __shared__ float U_s[TILE][LDH];
    __shared__ float V_s[TILE][LDH];

    const int tid = threadIdx.x;
    const int blk = blockIdx.x;
    const int b   = blk / NTP;
    int rem = blk % NTP;
    int ti = 0;
    while (rem >= NT - ti) { rem -= NT - ti; ++ti; }
    const int tj = ti + rem;                     // ti <= tj

    // ---- Phase 1: fold weights (redundant per block; ~4 dots of len 100 per thread)
    for (int idx = tid; idx < 2 * F_ * H_ + H_; idx += 256) {
        if (idx < 2 * F_ * H_) {
            const int r = idx / H_;              // 0..7 row of W1
            const int h = idx - r * H_;
            const float* w1r = W1 + r * H_;
            float s = 0.f;
            #pragma unroll 4
            for (int j = 0; j < H_; ++j) s = fmaf(w1r[j], W2[j * H_ + h], s);
            if (r < F_) A_s[r][h] = s; else Bm_s[r - F_][h] = s;
        } else {
            const int h = idx - 2 * F_ * H_;
            float s = b2[h];
            #pragma unroll 4
            for (int j = 0; j < H_; ++j) s = fmaf(b1[j], W2[j * H_ + h], s);
            c_s[h] = s;
        }
    }
    if (tid < H_) w3_s[tid] = W3[tid];
    __syncthreads();

    // ---- Phase 2: per-node U (i-tile, with c folded in) and V (j-tile) into LDS
    const int i0 = ti * TILE, j0 = tj * TILE;
    for (int idx = tid; idx < TILE * H_; idx += 256) {
        const int r = idx / H_;
        const int h = idx - r * H_;
        const float4 xi = ((const float4*)x)[b * N_ + i0 + r];
        U_s[r][h] = c_s[h] + xi.x * A_s[0][h] + xi.y * A_s[1][h]
                           + xi.z * A_s[2][h] + xi.w * A_s[3][h];
        const float4 xj = ((const float4*)x)[b * N_ + j0 + r];
        V_s[r][h] =        xj.x * Bm_s[0][h] + xj.y * Bm_s[1][h]
                         + xj.z * Bm_s[2][h] + xj.w * Bm_s[3][h];
    }
    __syncthreads();

    // ---- Phase 3: 2x2 register block of pairs per thread (32x32 tile / 256 thr)
    const int i2 = tid >> 4;          // 0..15
    const int j2 = tid & 15;          // 0..15
    const int ia = 2 * i2, ja = 2 * j2;
    float a00 = 0.f, a01 = 0.f, a10 = 0.f, a11 = 0.f;
    for (int h = 0; h < H_; ++h) {
        const float w  = w3_s[h];
        const float u0 = U_s[ia][h],     u1 = U_s[ia + 1][h];
        const float v0 = V_s[ja][h],     v1 = V_s[ja + 1][h];
        a00 = fmaf(w, fmaxf(u0 + v0, 0.f), a00);
        a01 = fmaf(w, fmaxf(u0 + v1, 0.f), a01);
        a10 = fmaf(w, fmaxf(u1 + v0, 0.f), a10);
        a11 = fmaf(w, fmaxf(u1 + v1, 0.f), a11);
    }
    const float b3v = b3[0];
    float* outb = out + b * PAIRS;
    const float accs[2][2] = {{a00, a01}, {a10, a11}};
    #pragma unroll
    for (int da = 0; da < 2; ++da) {
        #pragma unroll
        for (int dc = 0; dc < 2; ++dc) {
            const int gi = i0 + ia + da;
            const int gj = j0 + ja + dc;
            if (gi < gj) {   // masks lower half of diagonal tiles
                const int p = (gi * (2 * N_ - gi - 1)) / 2 + (gj - gi - 1);
                const float z = accs[da][dc] + b3v;
                outb[p] = 1.f / (1.f + expf(-z));
            }
        }
    }
}

extern "C" void kernel_launch(void* const* d_in, const int* in_sizes, int n_in,
                              void* d_out, int out_size, void* d_ws, size_t ws_size,
                              hipStream_t stream) {
    const float* x  = (const float*)d_in[0];
    // d_in[1] = in_hitnr: unused by the reference computation
    const float* W1 = (const float*)d_in[2];
    const float* b1 = (const float*)d_in[3];
    const float* W2 = (const float*)d_in[4];
    const float* b2 = (const float*)d_in[5];
    const float* W3 = (const float*)d_in[6];
    const float* b3 = (const float*)d_in[7];
    float* out = (float*)d_out;

    pairnet_fused<<<dim3(B_ * NTP), dim3(256), 0, stream>>>(
        x, W1, b1, W2, b2, W3, b3, out);
}

// Round 2
// 89.231 us; speedup vs baseline: 1.1386x; 1.1386x over previous
//
#include <hip/hip_runtime.h>
#include <math.h>

// out[b, p(i,j)] = sigmoid( relu( (x_i|x_j)@W1+b1 @ W2 + b2 ) @ W3 + b3 )
// Net is LINEAR until ReLU -> fold once:
//   AB[0:4]  = W1[0:4]@W2, AB[4:8] = W1[4:8]@W2  (each 4x100)
//   c        = b1@W2 + b2                         (100)
// Then U[b,i,h] = x[b,i]·AB[0:4][:,h] + c[h],  V[b,j,h] = x[b,j]·AB[4:8][:,h]
//   out = sigmoid( sum_h W3[h]*relu(U[i,h]+V[j,h]) + b3 )
//
// Kernel 1 folds weights into g_fold (once per launch, 1024 threads).
// Kernel 2: 64 batches x 36 upper-tri 16x16 tile-pairs = 2304 one-wave blocks.
// LDS layout [h/2][row][2] lets phase-3 read 2 rows x 2 h as one ds_read_b128.

namespace {
constexpr int B_    = 64;
constexpr int N_    = 128;
constexpr int H_    = 100;
constexpr int TILE  = 16;
constexpr int NT    = N_ / TILE;            // 8
constexpr int NTP   = NT * (NT + 1) / 2;    // 36
constexpr int PAIRS = N_ * (N_ - 1) / 2;    // 8128
// g_fold layout (floats): AB[8][100] @0, c[100] @800, w3[100] @900, b3 @1000
constexpr int FOLD_AB = 0;
constexpr int FOLD_C  = 800;
constexpr int FOLD_W3 = 900;
constexpr int FOLD_B3 = 1000;
}

__device__ float g_fold[1001];

__global__ __launch_bounds__(256)
void fold_weights(const float* __restrict__ W1, const float* __restrict__ b1,
                  const float* __restrict__ W2, const float* __restrict__ b2,
                  const float* __restrict__ W3, const float* __restrict__ b3)
{
    const int idx = blockIdx.x * 256 + threadIdx.x;   // 0..1023
    if (idx < 800) {
        const int r = idx / H_;           // W1 row 0..7
        const int h = idx - r * H_;
        const float* w1r = W1 + r * H_;
        float s = 0.f;
        #pragma unroll 5
        for (int j = 0; j < H_; ++j) s = fmaf(w1r[j], W2[j * H_ + h], s);
        g_fold[FOLD_AB + idx] = s;
    } else if (idx < 900) {
        const int h = idx - 800;
        float s = b2[h];
        #pragma unroll 5
        for (int j = 0; j < H_; ++j) s = fmaf(b1[j], W2[j * H_ + h], s);
        g_fold[FOLD_C + h] = s;
    } else if (idx < 1000) {
        g_fold[FOLD_W3 + (idx - 900)] = W3[idx - 900];
    } else if (idx == 1000) {
        g_fold[FOLD_B3] = b3[0];
    }
}

__global__ __launch_bounds__(64)
void pairnet_main(const float* __restrict__ x, float* __restrict__ out)
{
    // interleaved: element (row r, hidden h) at [(h>>1)*32 + r*2 + (h&1)]
    __shared__ float U_s[50 * 2 * TILE];    // 1600 floats
    __shared__ float V_s[50 * 2 * TILE];
    __shared__ float w3_s[H_];              // natural order == [h/2][2]

    const int tid = threadIdx.x;            // 0..63, one wave
    const int blk = blockIdx.x;
    const int b   = blk / NTP;
    int rem = blk - b * NTP;
    int ti = 0;
    while (rem >= NT - ti) { rem -= NT - ti; ++ti; }
    const int tj = ti + rem;                // ti <= tj
    const int i0 = ti * TILE, j0 = tj * TILE;

    for (int k = tid; k < H_; k += 64) w3_s[k] = g_fold[FOLD_W3 + k];

    // ---- build U (c folded in) and V tiles in interleaved layout
    const float4* x4 = (const float4*)x;    // x[b][n] is 4 floats
    for (int idx = tid; idx < TILE * H_; idx += 64) {
        const int r = idx & (TILE - 1);
        const int h = idx >> 4;
        const int a = (h >> 1) * (2 * TILE) + r * 2 + (h & 1);
        const float4 xi = x4[b * N_ + i0 + r];
        U_s[a] = g_fold[FOLD_C + h]
               + xi.x * g_fold[FOLD_AB + 0 * H_ + h]
               + xi.y * g_fold[FOLD_AB + 1 * H_ + h]
               + xi.z * g_fold[FOLD_AB + 2 * H_ + h]
               + xi.w * g_fold[FOLD_AB + 3 * H_ + h];
        const float4 xj = x4[b * N_ + j0 + r];
        V_s[a] = xj.x * g_fold[FOLD_AB + 4 * H_ + h]
               + xj.y * g_fold[FOLD_AB + 5 * H_ + h]
               + xj.z * g_fold[FOLD_AB + 6 * H_ + h]
               + xj.w * g_fold[FOLD_AB + 7 * H_ + h];
    }
    __syncthreads();

    // ---- 2x2 pairs per thread, 2 h per iter via b128 reads
    const int i2 = tid >> 3;                // 0..7
    const int j2 = tid & 7;                 // 0..7
    const int ia = 2 * i2, ja = 2 * j2;
    float a00 = 0.f, a01 = 0.f, a10 = 0.f, a11 = 0.f;
    #pragma unroll 2
    for (int h2 = 0; h2 < 50; ++h2) {
        const float2 w = *(const float2*)&w3_s[2 * h2];
        // u = {U[ia][h0], U[ia][h1], U[ia+1][h0], U[ia+1][h1]}
        const float4 u = *(const float4*)&U_s[h2 * 32 + ia * 2];
        const float4 v = *(const float4*)&V_s[h2 * 32 + ja * 2];
        a00 = fmaf(w.x, fmaxf(u.x + v.x, 0.f), fmaf(w.y, fmaxf(u.y + v.y, 0.f), a00));
        a01 = fmaf(w.x, fmaxf(u.x + v.z, 0.f), fmaf(w.y, fmaxf(u.y + v.w, 0.f), a01));
        a10 = fmaf(w.x, fmaxf(u.z + v.x, 0.f), fmaf(w.y, fmaxf(u.w + v.y, 0.f), a10));
        a11 = fmaf(w.x, fmaxf(u.z + v.z, 0.f), fmaf(w.y, fmaxf(u.w + v.w, 0.f), a11));
    }

    const float b3v = g_fold[FOLD_B3];
    float* outb = out + b * PAIRS;
    const float accs[2][2] = {{a00, a01}, {a10, a11}};
    #pragma unroll
    for (int da = 0; da < 2; ++da) {
        #pragma unroll
        for (int dc = 0; dc < 2; ++dc) {
            const int gi = i0 + ia + da;
            const int gj = j0 + ja + dc;
            if (gi < gj) {   // masks lower half of diagonal tiles
                const int p = (gi * (2 * N_ - gi - 1)) / 2 + (gj - gi - 1);
                const float z = accs[da][dc] + b3v;
                outb[p] = 1.f / (1.f + __expf(-z));
            }
        }
    }
}

extern "C" void kernel_launch(void* const* d_in, const int* in_sizes, int n_in,
                              void* d_out, int out_size, void* d_ws, size_t ws_size,
                              hipStream_t stream) {
    const float* x  = (const float*)d_in[0];
    // d_in[1] = in_hitnr: unused by the reference computation
    const float* W1 = (const float*)d_in[2];
    const float* b1 = (const float*)d_in[3];
    const float* W2 = (const float*)d_in[4];
    const float* b2 = (const float*)d_in[5];
    const float* W3 = (const float*)d_in[6];
    const float* b3 = (const float*)d_in[7];
    float* out = (float*)d_out;

    fold_weights<<<dim3(4), dim3(256), 0, stream>>>(W1, b1, W2, b2, W3, b3);
    pairnet_main<<<dim3(B_ * NTP), dim3(64), 0, stream>>>(x, out);
}